// Round 8
// baseline (469.942 us; speedup 1.0000x reference)
//
#include <hip/hip_runtime.h>
#include <math.h>

#define NB 4
#define L 512
#define DN 128
#define DP 64
#define H 8
#define HD 32
#define NH (H*HD)        // 256
#define AGG (NH + H*DP)  // 768
#define JC 64
#define NCH (L/JC)       // 8

// static device scratch
__device__ float g_q[NB*L*NH];
__device__ float g_k[NB*L*NH];
__device__ float g_v[NB*L*NH];
__device__ float g_agg[NB*L*AGG];
__device__ float g_nl[(size_t)NB*H*L*L];   // 33.5MB [n][h][i][j]

// ---------------- K1: QKV projection (4 rows / block) ----------------
__global__ __launch_bounds__(256) void k_qkv(const float* __restrict__ x,
    const float* __restrict__ Wq, const float* __restrict__ Wk,
    const float* __restrict__ Wv)
{
    __shared__ float xs[4*DN];
    int t = threadIdx.x;
    int rowbase = blockIdx.x * 4;
    #pragma unroll
    for (int it = 0; it < 2; ++it) {
        int flat = it*256 + t;
        xs[flat] = x[(size_t)rowbase*DN + flat];
    }
    __syncthreads();
    float aq[4], ak[4], av[4];
    #pragma unroll
    for (int r = 0; r < 4; ++r) { aq[r]=0.f; ak[r]=0.f; av[r]=0.f; }
    for (int d = 0; d < DN; ++d) {
        float wq = Wq[d*NH + t];
        float wk = Wk[d*NH + t];
        float wv = Wv[d*NH + t];
        #pragma unroll
        for (int r = 0; r < 4; ++r) {
            float xv = xs[r*DN + d];
            aq[r] = fmaf(xv, wq, aq[r]);
            ak[r] = fmaf(xv, wk, ak[r]);
            av[r] = fmaf(xv, wv, av[r]);
        }
    }
    #pragma unroll
    for (int r = 0; r < 4; ++r) {
        // fold (1/sqrt(HD))*sqrt(0.5) = 0.125 into q
        g_q[(size_t)(rowbase+r)*NH + t] = aq[r] * 0.125f;
        g_k[(size_t)(rowbase+r)*NH + t] = ak[r];
        g_v[(size_t)(rowbase+r)*NH + t] = av[r];
    }
}

// ---------------- K1.5: node logits GEMM: nl[n,h,i,j] = q[i]·k[j] ----------------
// qs stride 36 (rows 144B -> 16B aligned): broadcast float4 LDS reads (ops / 4)
__global__ __launch_bounds__(256) void k_qk()
{
    __shared__ __align__(16) float qs[16*36];
    int t = threadIdx.x;
    int bid = blockIdx.x;            // n*256 + h*32 + itile
    int n = bid >> 8;
    int h = (bid >> 5) & 7;
    int i0 = (bid & 31) << 4;
    if (t < 128) {
        int row = t >> 3, c4 = (t & 7) << 2;
        const float4 qv = *(const float4*)(g_q + (size_t)(n*L + i0 + row)*NH + h*HD + c4);
        *(float4*)&qs[row*36 + c4] = qv;
    }
    __syncthreads();
    #pragma unroll
    for (int jc = 0; jc < L; jc += 256) {
        int j = jc + t;
        float4 kr[8];
        const float4* kb = (const float4*)(g_k + (size_t)(n*L + j)*NH + h*HD);
        #pragma unroll
        for (int c4 = 0; c4 < 8; ++c4) kr[c4] = kb[c4];
        float* outb = g_nl + (size_t)((n*H + h)*L + i0)*L + j;
        #pragma unroll
        for (int i = 0; i < 16; ++i) {
            float a0 = 0.f, a1 = 0.f;
            #pragma unroll
            for (int c4 = 0; c4 < 8; c4 += 2) {
                float4 q0 = *(const float4*)&qs[i*36 + c4*4];
                float4 q1 = *(const float4*)&qs[i*36 + c4*4 + 4];
                a0 = fmaf(q0.x, kr[c4].x,   fmaf(q0.y, kr[c4].y,   a0));
                a0 = fmaf(q0.z, kr[c4].z,   fmaf(q0.w, kr[c4].w,   a0));
                a1 = fmaf(q1.x, kr[c4+1].x, fmaf(q1.y, kr[c4+1].y, a1));
                a1 = fmaf(q1.z, kr[c4+1].z, fmaf(q1.w, kr[c4+1].w, a1));
            }
            outb[(size_t)i*L] = a0 + a1;
        }
    }
}

// ---------------- K2: flash attention row, per-wave heads, 1 barrier/chunk ----
// (byte-identical to the round-5 version that passed the timing harness)
#define ATTN_STEP(c, cur, NC0, NC4, NN0, NN4)                                  \
  {                                                                            \
    __syncthreads();                                                           \
    if ((c)+1 < NCH) {                                                         \
      _Pragma("unroll")                                                        \
      for (int it2 = 0; it2 < 4; ++it2) {                                      \
        int f4 = it2*256 + t, jj = f4 >> 4, p4 = (f4 & 15) << 2;               \
        float* d = &zc[(cur)^1][jj*65 + p4];                                   \
        d[0]=zR[it2].x; d[1]=zR[it2].y; d[2]=zR[it2].z; d[3]=zR[it2].w;        \
      }                                                                        \
    }                                                                          \
    if ((c)+2 < NCH) {                                                         \
      const float4* s2 = (const float4*)(zrow + (size_t)((c)+2)*JC*DP);        \
      zR[0]=s2[t]; zR[1]=s2[256+t]; zR[2]=s2[512+t]; zR[3]=s2[768+t];          \
    }                                                                          \
    if ((c)+1 < NCH) {                                                         \
      int jg2 = ((c)+1)*JC + lane;                                             \
      NN0 = nl0[jg2]; NN4 = nl4[jg2];                                          \
    }                                                                          \
    float va = NC0, vb = NC4;                                                  \
    {                                                                          \
      const float* zr = &zc[cur][lane*65];                                     \
      _Pragma("unroll 16")                                                     \
      for (int pp = 0; pp < DP; ++pp) {                                        \
        float zv = zr[pp];                                                     \
        va = fmaf(zv, wp[pp*H + wv],     va);                                  \
        vb = fmaf(zv, wp[pp*H + wv + 4], vb);                                  \
      }                                                                        \
    }                                                                          \
    float ma = va, mb = vb;                                                    \
    _Pragma("unroll")                                                          \
    for (int o = 32; o > 0; o >>= 1) {                                         \
      ma = fmaxf(ma, __shfl_xor(ma, o));                                       \
      mb = fmaxf(mb, __shfl_xor(mb, o));                                       \
    }                                                                          \
    float mna = fmaxf(m0, ma), mnb = fmaxf(m1, mb);                            \
    float ra = __expf(m0 - mna), rb = __expf(m1 - mnb);                        \
    float ea = __expf(va - mna), eb = __expf(vb - mnb);                        \
    lcw[wv][0][lane] = ea; lcw[wv][1][lane] = eb;                              \
    float sa = ea, sb = eb;                                                    \
    _Pragma("unroll")                                                          \
    for (int o = 32; o > 0; o >>= 1) {                                         \
      sa += __shfl_xor(sa, o); sb += __shfl_xor(sb, o);                        \
    }                                                                          \
    s0 = s0*ra + sa; s1 = s1*rb + sb; m0 = mna; m1 = mnb;                      \
    float rsel = hiHalf ? rb : ra;                                             \
    accN *= rsel; accP0 *= ra; accP1 *= rb;                                    \
    const float* vbase = g_v + (size_t)(n*L + (c)*JC)*NH + hoff;               \
    const float* zcc = zc[cur];                                                \
    _Pragma("unroll 8")                                                        \
    for (int j = 0; j < JC; ++j) {                                             \
      float la = lcw[wv][0][j];                                                \
      float lb = lcw[wv][1][j];                                                \
      float vv = vbase[(size_t)j*NH];                                          \
      float zv = zcc[j*65 + lane];                                             \
      float lsel = hiHalf ? lb : la;                                           \
      accN  = fmaf(lsel, vv, accN);                                            \
      accP0 = fmaf(la, zv, accP0);                                             \
      accP1 = fmaf(lb, zv, accP1);                                             \
    }                                                                          \
  }

__global__ __launch_bounds__(256) void k_attn(const float* __restrict__ z,
    const float* __restrict__ Wp)
{
    __shared__ float zc[2][JC*65];   // double-buffered z chunk, stride 65
    __shared__ float lcw[4][2][JC];  // per-wave probs (no cross-wave use)
    __shared__ float wp[DP*H];       // Wp * sqrt(0.5)

    int t = threadIdx.x;
    int lane = t & 63;
    int wv = t >> 6;
    int row = blockIdx.x;            // n*L + i
    int n = row >> 9;
    int i = row & 511;
    const float* zrow = z + (size_t)row * (L*DP);

    wp[t]       = Wp[t]       * 0.70710678118654752f;
    wp[t + 256] = Wp[t + 256] * 0.70710678118654752f;

    const float* nl0 = g_nl + (size_t)((n*H + wv    )*L + i)*L;
    const float* nl4 = g_nl + (size_t)((n*H + wv + 4)*L + i)*L;

    // node-feat ownership: lane<32 -> head wv, dim lane; lane>=32 -> head wv+4, dim lane-32
    bool hiHalf = (lane >= 32);
    int hoff = wv*32 + lane + (hiHalf ? 96 : 0);

    float accN = 0.f, accP0 = 0.f, accP1 = 0.f;
    float m0 = -1e30f, s0 = 0.f, m1 = -1e30f, s1 = 0.f;

    float4 zR[4];
    float nlc0, nlc4, nln0, nln4;

    // prologue: chunk0 -> regs -> buf0; zR <- chunk1; nl chunk0
    {
        float4 zP[4];
        const float4* sp0 = (const float4*)zrow;
        #pragma unroll
        for (int it = 0; it < 4; ++it) zP[it] = sp0[it*256 + t];
        nlc0 = nl0[lane]; nlc4 = nl4[lane];
        #pragma unroll
        for (int it = 0; it < 4; ++it) {
            int f4 = it*256 + t, jj = f4 >> 4, p4 = (f4 & 15) << 2;
            float* d = &zc[0][jj*65 + p4];
            d[0]=zP[it].x; d[1]=zP[it].y; d[2]=zP[it].z; d[3]=zP[it].w;
        }
        const float4* sp1 = (const float4*)(zrow + (size_t)JC*DP);
        #pragma unroll
        for (int it = 0; it < 4; ++it) zR[it] = sp1[it*256 + t];
    }
    ATTN_STEP(0,0,nlc0,nlc4,nln0,nln4)
    ATTN_STEP(1,1,nln0,nln4,nlc0,nlc4)
    ATTN_STEP(2,0,nlc0,nlc4,nln0,nln4)
    ATTN_STEP(3,1,nln0,nln4,nlc0,nlc4)
    ATTN_STEP(4,0,nlc0,nlc4,nln0,nln4)
    ATTN_STEP(5,1,nln0,nln4,nlc0,nlc4)
    ATTN_STEP(6,0,nlc0,nlc4,nln0,nln4)
    ATTN_STEP(7,1,nln0,nln4,nlc0,nlc4)

    // finalize (all wave-local)
    float* arow = g_agg + (size_t)row * AGG;
    float sn = hiHalf ? s1 : s0;
    arow[hoff]                  = accN  * (1.f / sn);
    arow[NH + wv*DP + lane]     = accP0 * (1.f / s0);
    arow[NH + (wv+4)*DP + lane] = accP1 * (1.f / s1);
}

// ---------------- K3: transition + LN + MLP + LN (4 rows / block) ----------------
__global__ __launch_bounds__(256) void k_mlp(const float* __restrict__ x,
    const float* __restrict__ Wt1, const float* __restrict__ bt1,
    const float* __restrict__ g1, const float* __restrict__ b1,
    const float* __restrict__ W2a, const float* __restrict__ b2a,
    const float* __restrict__ W2b, const float* __restrict__ b2b,
    const float* __restrict__ g2, const float* __restrict__ b2,
    float* __restrict__ out)
{
    __shared__ float aggL[4*AGG];    // 12KB
    __shared__ float featsL[4*132];
    __shared__ float h1L[4*132];
    int t = threadIdx.x;
    int tc = t & 127;
    int tr = t >> 7;    // 0/1
    int lane = t & 63, wv = t >> 6;
    int rowbase = blockIdx.x * 4;

    #pragma unroll
    for (int it = 0; it < 12; ++it) {
        int flat = it*256 + t;
        aggL[flat] = g_agg[(size_t)rowbase*AGG + flat];
    }
    __syncthreads();
    // GEMM1: feats_pre = x + agg @ Wt1 + bt1 (rows tr*2+r)
    float acc[2] = {0.f,0.f};
    for (int kk = 0; kk < AGG; ++kk) {
        float w = Wt1[kk*DN + tc];
        #pragma unroll
        for (int r = 0; r < 2; ++r)
            acc[r] = fmaf(aggL[(tr*2+r)*AGG + kk], w, acc[r]);
    }
    float bt = bt1[tc];
    #pragma unroll
    for (int r = 0; r < 2; ++r) {
        int row = tr*2 + r;
        featsL[row*132 + tc] = acc[r] + bt + x[(size_t)(rowbase+row)*DN + tc];
    }
    __syncthreads();
    // LN1: wave wv handles row wv
    {
        int row = wv;
        float v0 = featsL[row*132 + lane];
        float v1 = featsL[row*132 + 64 + lane];
        float s = v0 + v1, s2 = v0*v0 + v1*v1;
        #pragma unroll
        for (int o = 32; o > 0; o >>= 1) {
            s  += __shfl_xor(s,  o);
            s2 += __shfl_xor(s2, o);
        }
        float mean = s * (1.f/128.f);
        float var  = s2 * (1.f/128.f) - mean*mean;
        float rstd = rsqrtf(var + 1e-5f);
        featsL[row*132 + lane]      = (v0 - mean)*rstd*g1[lane]      + b1[lane];
        featsL[row*132 + 64 + lane] = (v1 - mean)*rstd*g1[64+lane]   + b1[64+lane];
    }
    __syncthreads();
    // GEMM2 + relu
    float acc2[2] = {0.f,0.f};
    for (int kk = 0; kk < DN; ++kk) {
        float w = W2a[kk*DN + tc];
        #pragma unroll
        for (int r = 0; r < 2; ++r)
            acc2[r] = fmaf(featsL[(tr*2+r)*132 + kk], w, acc2[r]);
    }
    float ba = b2a[tc];
    #pragma unroll
    for (int r = 0; r < 2; ++r)
        h1L[(tr*2+r)*132 + tc] = fmaxf(acc2[r] + ba, 0.f);
    __syncthreads();
    // GEMM3 + residual
    float acc3[2] = {0.f,0.f};
    for (int kk = 0; kk < DN; ++kk) {
        float w = W2b[kk*DN + tc];
        #pragma unroll
        for (int r = 0; r < 2; ++r)
            acc3[r] = fmaf(h1L[(tr*2+r)*132 + kk], w, acc3[r]);
    }
    float bb = b2b[tc];
    #pragma unroll
    for (int r = 0; r < 2; ++r) {
        int row = tr*2 + r;
        featsL[row*132 + tc] = featsL[row*132 + tc] + acc3[r] + bb;
    }
    __syncthreads();
    // LN2 -> out
    {
        int row = wv;
        float v0 = featsL[row*132 + lane];
        float v1 = featsL[row*132 + 64 + lane];
        float s = v0 + v1, s2 = v0*v0 + v1*v1;
        #pragma unroll
        for (int o = 32; o > 0; o >>= 1) {
            s  += __shfl_xor(s,  o);
            s2 += __shfl_xor(s2, o);
        }
        float mean = s * (1.f/128.f);
        float var  = s2 * (1.f/128.f) - mean*mean;
        float rstd = rsqrtf(var + 1e-5f);
        out[(size_t)(rowbase+row)*DN + lane]      = (v0 - mean)*rstd*g2[lane]    + b2[lane];
        out[(size_t)(rowbase+row)*DN + 64 + lane] = (v1 - mean)*rstd*g2[64+lane] + b2[64+lane];
    }
}

extern "C" void kernel_launch(void* const* d_in, const int* in_sizes, int n_in,
                              void* d_out, int out_size, void* d_ws, size_t ws_size,
                              hipStream_t stream) {
    const float* x   = (const float*)d_in[0];
    const float* z   = (const float*)d_in[1];
    const float* Wq  = (const float*)d_in[2];
    const float* Wk  = (const float*)d_in[3];
    const float* Wv  = (const float*)d_in[4];
    const float* Wp  = (const float*)d_in[5];
    const float* Wt1 = (const float*)d_in[6];
    const float* bt1 = (const float*)d_in[7];
    const float* g1  = (const float*)d_in[8];
    const float* b1  = (const float*)d_in[9];
    const float* W2a = (const float*)d_in[10];
    const float* b2a = (const float*)d_in[11];
    const float* W2b = (const float*)d_in[12];
    const float* b2b = (const float*)d_in[13];
    const float* g2  = (const float*)d_in[14];
    const float* b2  = (const float*)d_in[15];
    float* out = (float*)d_out;

    k_qkv<<<NB*L/4, 256, 0, stream>>>(x, Wq, Wk, Wv);
    k_qk<<<NB*H*(L/16), 256, 0, stream>>>();
    k_attn<<<NB*L, 256, 0, stream>>>(z, Wp);
    k_mlp<<<NB*L/4, 256, 0, stream>>>(x, Wt1, bt1, g1, b1,
                                      W2a, b2a, W2b, b2b, g2, b2, out);
}

// Round 9
// 196.501 us; speedup vs baseline: 2.3915x; 2.3915x over previous
//
#include <hip/hip_runtime.h>
#include <math.h>

#define NB 4
#define L 512
#define DN 128
#define DP 64
#define H 8
#define HD 32
#define NH (H*HD)        // 256
#define AGG (NH + H*DP)  // 768
#define JC 64
#define NCH (L/JC)       // 8

// static device scratch
__device__ float g_qT[(size_t)NB*H*L*HD];  // [n][h][i][d], q*0.125
__device__ float g_kT[(size_t)NB*H*L*HD];  // [n][h][j][d]
__device__ float g_v[NB*L*NH];             // [n][j][h*32+d]
__device__ float g_agg[NB*L*AGG];
__device__ float g_nl[(size_t)NB*H*L*L];   // 33.5MB [n][h][i][j]

// ---------------- K1: QKV projection (4 rows / block) ----------------
__global__ __launch_bounds__(256) void k_qkv(const float* __restrict__ x,
    const float* __restrict__ Wq, const float* __restrict__ Wk,
    const float* __restrict__ Wv)
{
    __shared__ float xs[4*DN];
    int t = threadIdx.x;
    int rowbase = blockIdx.x * 4;
    #pragma unroll
    for (int it = 0; it < 2; ++it) {
        int flat = it*256 + t;
        xs[flat] = x[(size_t)rowbase*DN + flat];
    }
    __syncthreads();
    float aq[4], ak[4], av[4];
    #pragma unroll
    for (int r = 0; r < 4; ++r) { aq[r]=0.f; ak[r]=0.f; av[r]=0.f; }
    for (int d = 0; d < DN; ++d) {
        float wq = Wq[d*NH + t];
        float wk = Wk[d*NH + t];
        float wv = Wv[d*NH + t];
        #pragma unroll
        for (int r = 0; r < 4; ++r) {
            float xv = xs[r*DN + d];
            aq[r] = fmaf(xv, wq, aq[r]);
            ak[r] = fmaf(xv, wk, ak[r]);
            av[r] = fmaf(xv, wv, av[r]);
        }
    }
    int n2 = rowbase >> 9;
    int i0 = rowbase & 511;
    int h = t >> 5, d = t & 31;
    #pragma unroll
    for (int r = 0; r < 4; ++r) {
        // q/k transposed per-head rows ([n][h][i][d]); fold 0.125 into q
        size_t base = ((size_t)(n2*H + h)*L + i0 + r)*HD + d;
        g_qT[base] = aq[r] * 0.125f;
        g_kT[base] = ak[r];
        g_v[(size_t)(rowbase+r)*NH + t] = av[r];
    }
}

// ---------------- K1.5: node logits GEMM: nl[n,h,i,j] = q[i]·k[j] ----------------
// g_kT rows are lane-contiguous 128B blocks -> fully-consumed cache lines.
// qs stride 36 -> 16B-aligned float4 broadcast reads. No jc unroll (VGPR cap).
__global__ __launch_bounds__(256) void k_qk()
{
    __shared__ __align__(16) float qs[16*36];
    int t = threadIdx.x;
    int bid = blockIdx.x;            // n*256 + h*32 + itile
    int n = bid >> 8;
    int h = (bid >> 5) & 7;
    int i0 = (bid & 31) << 4;
    const float* qTb = g_qT + (size_t)((n*H + h)*L + i0)*HD;
    if (t < 128) {
        int row = t >> 3, c4 = (t & 7) << 2;
        float4 qv = *(const float4*)(qTb + row*HD + c4);
        *(float4*)&qs[row*36 + c4] = qv;
    }
    __syncthreads();
    const float* kTb = g_kT + (size_t)(n*H + h)*L*HD;
    for (int jc = 0; jc < L; jc += 256) {
        int j = jc + t;
        float4 kr[8];
        const float4* kb = (const float4*)(kTb + (size_t)j*HD);
        #pragma unroll
        for (int c4 = 0; c4 < 8; ++c4) kr[c4] = kb[c4];
        float* outb = g_nl + (size_t)((n*H + h)*L + i0)*L + j;
        #pragma unroll 4
        for (int i = 0; i < 16; ++i) {
            float a0 = 0.f, a1 = 0.f;
            #pragma unroll
            for (int c4 = 0; c4 < 8; c4 += 2) {
                float4 q0 = *(const float4*)&qs[i*36 + c4*4];
                float4 q1 = *(const float4*)&qs[i*36 + c4*4 + 4];
                a0 = fmaf(q0.x, kr[c4].x,   fmaf(q0.y, kr[c4].y,   a0));
                a0 = fmaf(q0.z, kr[c4].z,   fmaf(q0.w, kr[c4].w,   a0));
                a1 = fmaf(q1.x, kr[c4+1].x, fmaf(q1.y, kr[c4+1].y, a1));
                a1 = fmaf(q1.z, kr[c4+1].z, fmaf(q1.w, kr[c4+1].w, a1));
            }
            outb[(size_t)i*L] = a0 + a1;
        }
    }
}

// ---------------- K2: flash attention row, per-wave heads, 1 barrier/chunk ----
// (byte-identical to the round-5 version: 2/2 stable through the timing harness)
#define ATTN_STEP(c, cur, NC0, NC4, NN0, NN4)                                  \
  {                                                                            \
    __syncthreads();                                                           \
    if ((c)+1 < NCH) {                                                         \
      _Pragma("unroll")                                                        \
      for (int it2 = 0; it2 < 4; ++it2) {                                      \
        int f4 = it2*256 + t, jj = f4 >> 4, p4 = (f4 & 15) << 2;               \
        float* d = &zc[(cur)^1][jj*65 + p4];                                   \
        d[0]=zR[it2].x; d[1]=zR[it2].y; d[2]=zR[it2].z; d[3]=zR[it2].w;        \
      }                                                                        \
    }                                                                          \
    if ((c)+2 < NCH) {                                                         \
      const float4* s2 = (const float4*)(zrow + (size_t)((c)+2)*JC*DP);        \
      zR[0]=s2[t]; zR[1]=s2[256+t]; zR[2]=s2[512+t]; zR[3]=s2[768+t];          \
    }                                                                          \
    if ((c)+1 < NCH) {                                                         \
      int jg2 = ((c)+1)*JC + lane;                                             \
      NN0 = nl0[jg2]; NN4 = nl4[jg2];                                          \
    }                                                                          \
    float va = NC0, vb = NC4;                                                  \
    {                                                                          \
      const float* zr = &zc[cur][lane*65];                                     \
      _Pragma("unroll 16")                                                     \
      for (int pp = 0; pp < DP; ++pp) {                                        \
        float zv = zr[pp];                                                     \
        va = fmaf(zv, wp[pp*H + wv],     va);                                  \
        vb = fmaf(zv, wp[pp*H + wv + 4], vb);                                  \
      }                                                                        \
    }                                                                          \
    float ma = va, mb = vb;                                                    \
    _Pragma("unroll")                                                          \
    for (int o = 32; o > 0; o >>= 1) {                                         \
      ma = fmaxf(ma, __shfl_xor(ma, o));                                       \
      mb = fmaxf(mb, __shfl_xor(mb, o));                                       \
    }                                                                          \
    float mna = fmaxf(m0, ma), mnb = fmaxf(m1, mb);                            \
    float ra = __expf(m0 - mna), rb = __expf(m1 - mnb);                        \
    float ea = __expf(va - mna), eb = __expf(vb - mnb);                        \
    lcw[wv][0][lane] = ea; lcw[wv][1][lane] = eb;                              \
    float sa = ea, sb = eb;                                                    \
    _Pragma("unroll")                                                          \
    for (int o = 32; o > 0; o >>= 1) {                                         \
      sa += __shfl_xor(sa, o); sb += __shfl_xor(sb, o);                        \
    }                                                                          \
    s0 = s0*ra + sa; s1 = s1*rb + sb; m0 = mna; m1 = mnb;                      \
    float rsel = hiHalf ? rb : ra;                                             \
    accN *= rsel; accP0 *= ra; accP1 *= rb;                                    \
    const float* vbase = g_v + (size_t)(n*L + (c)*JC)*NH + hoff;               \
    const float* zcc = zc[cur];                                                \
    _Pragma("unroll 8")                                                        \
    for (int j = 0; j < JC; ++j) {                                             \
      float la = lcw[wv][0][j];                                                \
      float lb = lcw[wv][1][j];                                                \
      float vv = vbase[(size_t)j*NH];                                          \
      float zv = zcc[j*65 + lane];                                             \
      float lsel = hiHalf ? lb : la;                                           \
      accN  = fmaf(lsel, vv, accN);                                            \
      accP0 = fmaf(la, zv, accP0);                                             \
      accP1 = fmaf(lb, zv, accP1);                                             \
    }                                                                          \
  }

__global__ __launch_bounds__(256) void k_attn(const float* __restrict__ z,
    const float* __restrict__ Wp)
{
    __shared__ float zc[2][JC*65];   // double-buffered z chunk, stride 65
    __shared__ float lcw[4][2][JC];  // per-wave probs (no cross-wave use)
    __shared__ float wp[DP*H];       // Wp * sqrt(0.5)

    int t = threadIdx.x;
    int lane = t & 63;
    int wv = t >> 6;
    int row = blockIdx.x;            // n*L + i
    int n = row >> 9;
    int i = row & 511;
    const float* zrow = z + (size_t)row * (L*DP);

    wp[t]       = Wp[t]       * 0.70710678118654752f;
    wp[t + 256] = Wp[t + 256] * 0.70710678118654752f;

    const float* nl0 = g_nl + (size_t)((n*H + wv    )*L + i)*L;
    const float* nl4 = g_nl + (size_t)((n*H + wv + 4)*L + i)*L;

    // node-feat ownership: lane<32 -> head wv, dim lane; lane>=32 -> head wv+4, dim lane-32
    bool hiHalf = (lane >= 32);
    int hoff = wv*32 + lane + (hiHalf ? 96 : 0);

    float accN = 0.f, accP0 = 0.f, accP1 = 0.f;
    float m0 = -1e30f, s0 = 0.f, m1 = -1e30f, s1 = 0.f;

    float4 zR[4];
    float nlc0, nlc4, nln0, nln4;

    // prologue: chunk0 -> regs -> buf0; zR <- chunk1; nl chunk0
    {
        float4 zP[4];
        const float4* sp0 = (const float4*)zrow;
        #pragma unroll
        for (int it = 0; it < 4; ++it) zP[it] = sp0[it*256 + t];
        nlc0 = nl0[lane]; nlc4 = nl4[lane];
        #pragma unroll
        for (int it = 0; it < 4; ++it) {
            int f4 = it*256 + t, jj = f4 >> 4, p4 = (f4 & 15) << 2;
            float* d = &zc[0][jj*65 + p4];
            d[0]=zP[it].x; d[1]=zP[it].y; d[2]=zP[it].z; d[3]=zP[it].w;
        }
        const float4* sp1 = (const float4*)(zrow + (size_t)JC*DP);
        #pragma unroll
        for (int it = 0; it < 4; ++it) zR[it] = sp1[it*256 + t];
    }
    ATTN_STEP(0,0,nlc0,nlc4,nln0,nln4)
    ATTN_STEP(1,1,nln0,nln4,nlc0,nlc4)
    ATTN_STEP(2,0,nlc0,nlc4,nln0,nln4)
    ATTN_STEP(3,1,nln0,nln4,nlc0,nlc4)
    ATTN_STEP(4,0,nlc0,nlc4,nln0,nln4)
    ATTN_STEP(5,1,nln0,nln4,nlc0,nlc4)
    ATTN_STEP(6,0,nlc0,nlc4,nln0,nln4)
    ATTN_STEP(7,1,nln0,nln4,nlc0,nlc4)

    // finalize (all wave-local)
    float* arow = g_agg + (size_t)row * AGG;
    float sn = hiHalf ? s1 : s0;
    arow[hoff]                  = accN  * (1.f / sn);
    arow[NH + wv*DP + lane]     = accP0 * (1.f / s0);
    arow[NH + (wv+4)*DP + lane] = accP1 * (1.f / s1);
}

// ---------------- K3: transition + LN + MLP + LN (4 rows / block) ----------------
__global__ __launch_bounds__(256) void k_mlp(const float* __restrict__ x,
    const float* __restrict__ Wt1, const float* __restrict__ bt1,
    const float* __restrict__ g1, const float* __restrict__ b1,
    const float* __restrict__ W2a, const float* __restrict__ b2a,
    const float* __restrict__ W2b, const float* __restrict__ b2b,
    const float* __restrict__ g2, const float* __restrict__ b2,
    float* __restrict__ out)
{
    __shared__ float aggL[4*AGG];    // 12KB
    __shared__ float featsL[4*132];
    __shared__ float h1L[4*132];
    int t = threadIdx.x;
    int tc = t & 127;
    int tr = t >> 7;    // 0/1
    int lane = t & 63, wv = t >> 6;
    int rowbase = blockIdx.x * 4;

    #pragma unroll
    for (int it = 0; it < 12; ++it) {
        int flat = it*256 + t;
        aggL[flat] = g_agg[(size_t)rowbase*AGG + flat];
    }
    __syncthreads();
    // GEMM1: feats_pre = x + agg @ Wt1 + bt1 (rows tr*2+r)
    float acc[2] = {0.f,0.f};
    for (int kk = 0; kk < AGG; ++kk) {
        float w = Wt1[kk*DN + tc];
        #pragma unroll
        for (int r = 0; r < 2; ++r)
            acc[r] = fmaf(aggL[(tr*2+r)*AGG + kk], w, acc[r]);
    }
    float bt = bt1[tc];
    #pragma unroll
    for (int r = 0; r < 2; ++r) {
        int row = tr*2 + r;
        featsL[row*132 + tc] = acc[r] + bt + x[(size_t)(rowbase+row)*DN + tc];
    }
    __syncthreads();
    // LN1: wave wv handles row wv
    {
        int row = wv;
        float v0 = featsL[row*132 + lane];
        float v1 = featsL[row*132 + 64 + lane];
        float s = v0 + v1, s2 = v0*v0 + v1*v1;
        #pragma unroll
        for (int o = 32; o > 0; o >>= 1) {
            s  += __shfl_xor(s,  o);
            s2 += __shfl_xor(s2, o);
        }
        float mean = s * (1.f/128.f);
        float var  = s2 * (1.f/128.f) - mean*mean;
        float rstd = rsqrtf(var + 1e-5f);
        featsL[row*132 + lane]      = (v0 - mean)*rstd*g1[lane]      + b1[lane];
        featsL[row*132 + 64 + lane] = (v1 - mean)*rstd*g1[64+lane]   + b1[64+lane];
    }
    __syncthreads();
    // GEMM2 + relu
    float acc2[2] = {0.f,0.f};
    for (int kk = 0; kk < DN; ++kk) {
        float w = W2a[kk*DN + tc];
        #pragma unroll
        for (int r = 0; r < 2; ++r)
            acc2[r] = fmaf(featsL[(tr*2+r)*132 + kk], w, acc2[r]);
    }
    float ba = b2a[tc];
    #pragma unroll
    for (int r = 0; r < 2; ++r)
        h1L[(tr*2+r)*132 + tc] = fmaxf(acc2[r] + ba, 0.f);
    __syncthreads();
    // GEMM3 + residual
    float acc3[2] = {0.f,0.f};
    for (int kk = 0; kk < DN; ++kk) {
        float w = W2b[kk*DN + tc];
        #pragma unroll
        for (int r = 0; r < 2; ++r)
            acc3[r] = fmaf(h1L[(tr*2+r)*132 + kk], w, acc3[r]);
    }
    float bb = b2b[tc];
    #pragma unroll
    for (int r = 0; r < 2; ++r) {
        int row = tr*2 + r;
        featsL[row*132 + tc] = featsL[row*132 + tc] + acc3[r] + bb;
    }
    __syncthreads();
    // LN2 -> out
    {
        int row = wv;
        float v0 = featsL[row*132 + lane];
        float v1 = featsL[row*132 + 64 + lane];
        float s = v0 + v1, s2 = v0*v0 + v1*v1;
        #pragma unroll
        for (int o = 32; o > 0; o >>= 1) {
            s  += __shfl_xor(s,  o);
            s2 += __shfl_xor(s2, o);
        }
        float mean = s * (1.f/128.f);
        float var  = s2 * (1.f/128.f) - mean*mean;
        float rstd = rsqrtf(var + 1e-5f);
        out[(size_t)(rowbase+row)*DN + lane]      = (v0 - mean)*rstd*g2[lane]    + b2[lane];
        out[(size_t)(rowbase+row)*DN + 64 + lane] = (v1 - mean)*rstd*g2[64+lane] + b2[64+lane];
    }
}

extern "C" void kernel_launch(void* const* d_in, const int* in_sizes, int n_in,
                              void* d_out, int out_size, void* d_ws, size_t ws_size,
                              hipStream_t stream) {
    const float* x   = (const float*)d_in[0];
    const float* z   = (const float*)d_in[1];
    const float* Wq  = (const float*)d_in[2];
    const float* Wk  = (const float*)d_in[3];
    const float* Wv  = (const float*)d_in[4];
    const float* Wp  = (const float*)d_in[5];
    const float* Wt1 = (const float*)d_in[6];
    const float* bt1 = (const float*)d_in[7];
    const float* g1  = (const float*)d_in[8];
    const float* b1  = (const float*)d_in[9];
    const float* W2a = (const float*)d_in[10];
    const float* b2a = (const float*)d_in[11];
    const float* W2b = (const float*)d_in[12];
    const float* b2b = (const float*)d_in[13];
    const float* g2  = (const float*)d_in[14];
    const float* b2  = (const float*)d_in[15];
    float* out = (float*)d_out;

    k_qkv<<<NB*L/4, 256, 0, stream>>>(x, Wq, Wk, Wv);
    k_qk<<<NB*H*(L/16), 256, 0, stream>>>();
    k_attn<<<NB*L, 256, 0, stream>>>(z, Wp);
    k_mlp<<<NB*L/4, 256, 0, stream>>>(x, Wt1, bt1, g1, b1,
                                      W2a, b2a, W2b, b2b, g2, b2, out);
}